// Round 5
// baseline (300.864 us; speedup 1.0000x reference)
//
#include <hip/hip_runtime.h>

// Gate3: out[r][c] = g(x1[r][c>>2]) + g(x2[r][c>>1]) + g(x3[r][c]),
// g(x) = sigmoid(x*w + b) * x; out (B,16,1) == flat (B*16,) fp32.
//
// Memory-bound streaming: 224 MiB read + 128 MiB write, roofline ~59 us
// at 6.3 TB/s. One thread per QUARTER-row (i = row*4 + q): every access
// unit-stride across lanes, 100% utilized:
//   x1: scalar  x1[i]   (4 B/lane)
//   x2: float2  x2[2i]  (8 B/lane)
//   x3: float4  x3[4i]  (16 B/lane)
//   out: float4 out[4i] (16 B/lane)
// 7 gate evals/thread; gates of repeated cols computed once.
//
// Round-4 post-mortem: harness fills run 537 MB @ 6.7 TB/s (~80 us) and
// dominate the graph; gate3's own dispatch is <80 us. Changes this round:
//  - dropped nontemporal hints (speculative-negative; cache path is fine)
//  - __frcp_rn (slow correctly-rounded div sequence) -> v_rcp_f32
// Round-3 note: never pass floats through readfirstlane (int-only builtin).

typedef float v2f __attribute__((ext_vector_type(2)));
typedef float v4f __attribute__((ext_vector_type(4)));

__device__ __forceinline__ float gate(float x, float w, float b) {
    float z = fmaf(x, w, b);
    float s = __builtin_amdgcn_rcpf(1.0f + __expf(-z));   // sigmoid, v_rcp_f32
    return s * x;
}

__global__ __launch_bounds__(256) void gate3_kernel(
    const float* __restrict__ x1,   // (B,4)  flat
    const v2f*  __restrict__ x2,    // (B,8)  flat, as float2
    const v4f*  __restrict__ x3,    // (B,16) flat, as float4
    const float* __restrict__ Wp,
    const float* __restrict__ bp,
    v4f* __restrict__ out,          // (B,16) flat, as float4
    int nquads)                     // B*4
{
    const float w = Wp[0];
    const float b = bp[0];

    const int stride = gridDim.x * blockDim.x;
    for (int i = blockIdx.x * blockDim.x + threadIdx.x; i < nquads; i += stride) {
        float a  = x1[i];
        v2f  b2  = x2[i];
        v4f  c4  = x3[i];

        float ga  = gate(a, w, b);
        float gb0 = gate(b2.x, w, b);
        float gb1 = gate(b2.y, w, b);

        v4f o;
        o.x = ga + gb0 + gate(c4.x, w, b);
        o.y = ga + gb0 + gate(c4.y, w, b);
        o.z = ga + gb1 + gate(c4.z, w, b);
        o.w = ga + gb1 + gate(c4.w, w, b);

        out[i] = o;
    }
}

extern "C" void kernel_launch(void* const* d_in, const int* in_sizes, int n_in,
                              void* d_out, int out_size, void* d_ws, size_t ws_size,
                              hipStream_t stream) {
    const float* x1 = (const float*)d_in[0];
    const v2f*   x2 = (const v2f*)d_in[1];
    const v4f*   x3 = (const v4f*)d_in[2];
    const float* W  = (const float*)d_in[3];
    const float* b  = (const float*)d_in[4];
    v4f* out = (v4f*)d_out;

    int nquads = in_sizes[0];             // B*4 = 8388608
    int block  = 256;
    int grid   = 2048;                    // 256 CUs x 8 blocks, grid-stride x16

    gate3_kernel<<<grid, block, 0, stream>>>(x1, x2, x3, W, b, out, nquads);
}

// Round 8
// 280.826 us; speedup vs baseline: 1.0714x; 1.0714x over previous
//
#include <hip/hip_runtime.h>

// Gate3: out[r][c] = g(x1[r][c>>2]) + g(x2[r][c>>1]) + g(x3[r][c]),
// g(x) = sigmoid(x*w + b) * x; out (B,16,1) == flat (B*16,) fp32.
//
// Memory-bound streaming: 224 MiB read + 128 MiB write, roofline ~59 us
// at 6.3 TB/s. One thread per QUARTER-row (i = row*4 + q): every access
// unit-stride across lanes, 100% utilized:
//   x1: scalar  x1[i]   (4 B/lane)
//   x2: float2  x2[2i]  (8 B/lane)
//   x3: float4  x3[4i]  (16 B/lane)
//   out: float4 out[4i] (16 B/lane)
//
// Round-5 post-mortem (measured, keep this): NONTEMPORAL HINTS ARE LOAD-
// BEARING here. Without NT: 106 us, HBM 2.4 TB/s, VALUBusy 12% (latency/
// cache-allocate bound — output stores thrash input lines in L2/L3).
// With NT (round 4): dispatch <79.5 us. Zero-reuse streaming => always NT.
// Round-3 note: never pass floats through readfirstlane (int-only builtin).

typedef float v2f __attribute__((ext_vector_type(2)));
typedef float v4f __attribute__((ext_vector_type(4)));

__device__ __forceinline__ float gate(float x, float w, float b) {
    float z = fmaf(x, w, b);
    float s = __builtin_amdgcn_rcpf(1.0f + __expf(-z));   // sigmoid, v_rcp_f32
    return s * x;
}

__global__ __launch_bounds__(256) void gate3_kernel(
    const float* __restrict__ x1,   // (B,4)  flat
    const v2f*  __restrict__ x2,    // (B,8)  flat, as float2
    const v4f*  __restrict__ x3,    // (B,16) flat, as float4
    const float* __restrict__ Wp,
    const float* __restrict__ bp,
    v4f* __restrict__ out,          // (B,16) flat, as float4
    int nquads)                     // B*4
{
    const float w = Wp[0];
    const float b = bp[0];

    const int stride = gridDim.x * blockDim.x;
    for (int i = blockIdx.x * blockDim.x + threadIdx.x; i < nquads; i += stride) {
        float a  = __builtin_nontemporal_load(&x1[i]);
        v2f  b2  = __builtin_nontemporal_load(&x2[i]);
        v4f  c4  = __builtin_nontemporal_load(&x3[i]);

        float ga  = gate(a, w, b);
        float gb0 = gate(b2.x, w, b);
        float gb1 = gate(b2.y, w, b);

        v4f o;
        o.x = ga + gb0 + gate(c4.x, w, b);
        o.y = ga + gb0 + gate(c4.y, w, b);
        o.z = ga + gb1 + gate(c4.z, w, b);
        o.w = ga + gb1 + gate(c4.w, w, b);

        __builtin_nontemporal_store(o, &out[i]);
    }
}

extern "C" void kernel_launch(void* const* d_in, const int* in_sizes, int n_in,
                              void* d_out, int out_size, void* d_ws, size_t ws_size,
                              hipStream_t stream) {
    const float* x1 = (const float*)d_in[0];
    const v2f*   x2 = (const v2f*)d_in[1];
    const v4f*   x3 = (const v4f*)d_in[2];
    const float* W  = (const float*)d_in[3];
    const float* b  = (const float*)d_in[4];
    v4f* out = (v4f*)d_out;

    int nquads = in_sizes[0];             // B*4 = 8388608
    int block  = 256;
    int grid   = 2048;                    // 256 CUs x 8 blocks, grid-stride x16

    gate3_kernel<<<grid, block, 0, stream>>>(x1, x2, x3, W, b, out, nquads);
}